// Round 1
// baseline (934.180 us; speedup 1.0000x reference)
//
#include <hip/hip_runtime.h>
#include <stdint.h>

typedef unsigned short u16;
typedef short v8s __attribute__((ext_vector_type(8)));
typedef float v4f __attribute__((ext_vector_type(4)));

typedef __attribute__((address_space(1))) uint32_t g_u32;
typedef __attribute__((address_space(3))) uint32_t l_u32;

// async global->LDS, 16B per lane; LDS dest = wave-uniform base + lane*16
__device__ __forceinline__ void glds16(const void* g, void* l) {
    __builtin_amdgcn_global_load_lds((const g_u32*)g, (l_u32*)l, 16, 0, 0);
}

// scalar fp32 -> bf16, round-to-nearest-even
__device__ __forceinline__ u16 f2b(float f) {
    uint32_t u = __builtin_bit_cast(uint32_t, f);
    u += 0x7FFFu + ((u >> 16) & 1u);
    return (u16)(u >> 16);
}

// pack two fp32 -> two bf16 in one u32 (round-half-up: +0x8000 then take high16)
__device__ __forceinline__ uint32_t pk2(float a, float b) {
    uint32_t ua = __builtin_bit_cast(uint32_t, a) + 0x8000u;
    uint32_t ub = __builtin_bit_cast(uint32_t, b) + 0x8000u;
    return __builtin_amdgcn_perm(ub, ua, 0x07060302u);  // lo = ua.hi16, hi = ub.hi16
}

#define MTOT  32768
#define HDIM  768
#define KDIM  2000
#define KPAD  2016

// ---------------- K0: convert weights to bf16 (proj_w padded K 2000->2016) --------------
__global__ __launch_bounds__(256) void cvt_weights(
    const float* __restrict__ pw, const float* __restrict__ nw,
    u16* __restrict__ Wb, u16* __restrict__ NWb)
{
    const int h = blockIdx.x;  // 768 blocks
    const float* src = pw + (size_t)h * KDIM;
    u16* dst = Wb + (size_t)h * KPAD;
    for (int k = threadIdx.x; k < KPAD; k += 256)
        dst[k] = (k < KDIM) ? f2b(src[k]) : (u16)0;
    const float* s2 = nw + (size_t)h * HDIM;
    u16* d2 = NWb + (size_t)h * HDIM;
    for (int k = threadIdx.x; k < HDIM; k += 256)
        d2[k] = f2b(s2[k]);
}

// ---------------- K1: GEMM1  x[m,h] = A[m,:] . Wb[h,:]  + bias + 5 embedding gathers ----
// 128x128 tile, BK=32, 4 waves each 64x64 (4x4 of 16x16x32 MFMA).
// A (fp32) staged via VGPR + convert; W (bf16) staged via global_load_lds.
__global__ __launch_bounds__(256) void gemm1(
    const float* __restrict__ A, const u16* __restrict__ Wb,
    const float* __restrict__ pb,
    const int* __restrict__ i_ty, const int* __restrict__ i_la,
    const int* __restrict__ i_op, const int* __restrict__ i_in, const int* __restrict__ i_ou,
    const float* __restrict__ te, const float* __restrict__ le, const float* __restrict__ oe,
    const float* __restrict__ ie, const float* __restrict__ ooe,
    u16* __restrict__ Xb)
{
    __shared__ __align__(16) u16 As[128 * 32];
    __shared__ __align__(16) u16 Bs[128 * 32];

    // XCD-aware swizzle: 6 N-tiles of one M-panel land on the same XCD back-to-back
    const int bid = blockIdx.x;            // 1536 = 256 m-tiles * 6 n-tiles
    const int slot = bid >> 3;             // 0..191
    const int mt = (bid & 7) * 32 + slot / 6;
    const int nt = slot % 6;
    const int m_base = mt * 128, n_base = nt * 128;

    const int tid = threadIdx.x;
    const int w = tid >> 6, lane = tid & 63;
    const int lm = lane & 15, quad = lane >> 4;
    const int wm = (w >> 1) * 64, wn = (w & 1) * 64;

    // A staging: thread t -> row t/2, 16-float chunk (t&1)
    const int arow = tid >> 1, ahalf = tid & 1;
    const float* aSrc = A + (size_t)(m_base + arow) * KDIM + ahalf * 16;
    u16* aDst = &As[arow * 32 + ahalf * 16];

    // W staging: wave w covers h-rows [w*32, w*32+32), 2 glds instrs
    const u16* wSrc = Wb + (size_t)(n_base + w * 32 + (lane >> 2)) * KPAD + (lane & 3) * 8;
    u16* wDst0 = &Bs[(w * 32) * 32];
    u16* wDst1 = &Bs[(w * 32 + 16) * 32];

    v4f acc[4][4];
#pragma unroll
    for (int i = 0; i < 4; i++)
#pragma unroll
        for (int j = 0; j < 4; j++) acc[i][j] = (v4f){0.f, 0.f, 0.f, 0.f};

    for (int kb = 0; kb < KPAD / 32; ++kb) {
        float4 r0, r1, r2, r3;
        const int k0 = kb * 32 + ahalf * 16;
        if (k0 < KDIM) {
            const float4* p = (const float4*)(aSrc + kb * 32);
            r0 = p[0]; r1 = p[1]; r2 = p[2]; r3 = p[3];
        } else {
            r0 = r1 = r2 = r3 = make_float4(0.f, 0.f, 0.f, 0.f);
        }
        __syncthreads();  // prev iter's LDS reads done
        glds16(wSrc + kb * 32, wDst0);
        glds16(wSrc + kb * 32 + 16 * KPAD, wDst1);
        int4 pa, pc;
        pa.x = (int)pk2(r0.x, r0.y); pa.y = (int)pk2(r0.z, r0.w);
        pa.z = (int)pk2(r1.x, r1.y); pa.w = (int)pk2(r1.z, r1.w);
        pc.x = (int)pk2(r2.x, r2.y); pc.y = (int)pk2(r2.z, r2.w);
        pc.z = (int)pk2(r3.x, r3.y); pc.w = (int)pk2(r3.z, r3.w);
        *(int4*)aDst = pa;
        *(int4*)(aDst + 8) = pc;
        __syncthreads();  // drains vmcnt (glds) + lgkm (ds_write)

        v8s af[4], bf[4];
#pragma unroll
        for (int i = 0; i < 4; i++)
            af[i] = *(const v8s*)&As[(wm + i * 16 + lm) * 32 + quad * 8];
#pragma unroll
        for (int j = 0; j < 4; j++)
            bf[j] = *(const v8s*)&Bs[(wn + j * 16 + lm) * 32 + quad * 8];
#pragma unroll
        for (int i = 0; i < 4; i++)
#pragma unroll
            for (int j = 0; j < 4; j++)
                acc[i][j] = __builtin_amdgcn_mfma_f32_16x16x32_bf16(af[i], bf[j], acc[i][j], 0, 0, 0);
    }

    // epilogue: + proj_b + 5 table gathers, write bf16 x
#pragma unroll
    for (int i = 0; i < 4; i++) {
#pragma unroll
        for (int r = 0; r < 4; r++) {
            const int row = m_base + wm + i * 16 + quad * 4 + r;
            const int ty = i_ty[row], la = i_la[row], op = i_op[row];
            const int di = i_in[row], dо = i_ou[row];
            const float* pte = te + (size_t)ty * HDIM;
            const float* ple = le + (size_t)la * HDIM;
            const float* poe = oe + (size_t)op * HDIM;
            const float* pie = ie + (size_t)di * HDIM;
            const float* pou = ooe + (size_t)dо * HDIM;
            u16* orow = Xb + (size_t)row * HDIM;
#pragma unroll
            for (int j = 0; j < 4; j++) {
                const int col = n_base + wn + j * 16 + lm;
                float v = acc[i][j][r] + pb[col] + pte[col] + ple[col] + poe[col] + pie[col] + pou[col];
                orow[col] = f2b(v);
            }
        }
    }
}

// ---------------- K2: GEMM2  y[m,g] = xb[m,:] . NWb[g,:] + neg_b  (all bf16 MFMA) -------
__global__ __launch_bounds__(256) void gemm2(
    const u16* __restrict__ Xb, const u16* __restrict__ NWb,
    const float* __restrict__ nb, u16* __restrict__ Yb)
{
    __shared__ __align__(16) u16 As[128 * 32];
    __shared__ __align__(16) u16 Bs[128 * 32];

    const int bid = blockIdx.x;
    const int slot = bid >> 3;
    const int mt = (bid & 7) * 32 + slot / 6;
    const int nt = slot % 6;
    const int m_base = mt * 128, n_base = nt * 128;

    const int tid = threadIdx.x;
    const int w = tid >> 6, lane = tid & 63;
    const int lm = lane & 15, quad = lane >> 4;
    const int wm = (w >> 1) * 64, wn = (w & 1) * 64;

    const u16* aSrc = Xb + (size_t)(m_base + w * 32 + (lane >> 2)) * HDIM + (lane & 3) * 8;
    u16* aDst0 = &As[(w * 32) * 32];
    u16* aDst1 = &As[(w * 32 + 16) * 32];
    const u16* wSrc = NWb + (size_t)(n_base + w * 32 + (lane >> 2)) * HDIM + (lane & 3) * 8;
    u16* wDst0 = &Bs[(w * 32) * 32];
    u16* wDst1 = &Bs[(w * 32 + 16) * 32];

    v4f acc[4][4];
#pragma unroll
    for (int i = 0; i < 4; i++)
#pragma unroll
        for (int j = 0; j < 4; j++) acc[i][j] = (v4f){0.f, 0.f, 0.f, 0.f};

    for (int kb = 0; kb < HDIM / 32; ++kb) {
        __syncthreads();
        glds16(aSrc + kb * 32, aDst0);
        glds16(aSrc + kb * 32 + 16 * HDIM, aDst1);
        glds16(wSrc + kb * 32, wDst0);
        glds16(wSrc + kb * 32 + 16 * HDIM, wDst1);
        __syncthreads();

        v8s af[4], bf[4];
#pragma unroll
        for (int i = 0; i < 4; i++)
            af[i] = *(const v8s*)&As[(wm + i * 16 + lm) * 32 + quad * 8];
#pragma unroll
        for (int j = 0; j < 4; j++)
            bf[j] = *(const v8s*)&Bs[(wn + j * 16 + lm) * 32 + quad * 8];
#pragma unroll
        for (int i = 0; i < 4; i++)
#pragma unroll
            for (int j = 0; j < 4; j++)
                acc[i][j] = __builtin_amdgcn_mfma_f32_16x16x32_bf16(af[i], bf[j], acc[i][j], 0, 0, 0);
    }

#pragma unroll
    for (int i = 0; i < 4; i++) {
#pragma unroll
        for (int r = 0; r < 4; r++) {
            const int row = m_base + wm + i * 16 + quad * 4 + r;
            u16* orow = Yb + (size_t)row * HDIM;
#pragma unroll
            for (int j = 0; j < 4; j++) {
                const int col = n_base + wn + j * 16 + lm;
                orow[col] = f2b(acc[i][j][r] + nb[col]);
            }
        }
    }
}

// ---------------- K3: select (negs) + LayerNorm, one wave per row -----------------------
__global__ __launch_bounds__(256) void ln_k(
    const u16* __restrict__ Xb, const u16* __restrict__ Yb,
    const int* __restrict__ negs,
    const float* __restrict__ g, const float* __restrict__ b,
    float* __restrict__ out)
{
    const int w = threadIdx.x >> 6, lane = threadIdx.x & 63;
    const int row = blockIdx.x * 4 + w;
    const u16* src = ((negs[row] == 1) ? Yb : Xb) + (size_t)row * HDIM;

    float v[12];
    float s = 0.f, ss = 0.f;
#pragma unroll
    for (int p = 0; p < 3; p++) {
        uint2 u = *(const uint2*)(src + (p * 64 + lane) * 4);
        float f0 = __builtin_bit_cast(float, u.x << 16);
        float f1 = __builtin_bit_cast(float, u.x & 0xFFFF0000u);
        float f2 = __builtin_bit_cast(float, u.y << 16);
        float f3 = __builtin_bit_cast(float, u.y & 0xFFFF0000u);
        v[p * 4 + 0] = f0; v[p * 4 + 1] = f1; v[p * 4 + 2] = f2; v[p * 4 + 3] = f3;
        s += f0 + f1 + f2 + f3;
        ss += f0 * f0 + f1 * f1 + f2 * f2 + f3 * f3;
    }
#pragma unroll
    for (int off = 1; off < 64; off <<= 1) {
        s += __shfl_xor(s, off);
        ss += __shfl_xor(ss, off);
    }
    const float mean = s * (1.f / (float)HDIM);
    const float var = ss * (1.f / (float)HDIM) - mean * mean;
    const float rs = rsqrtf(var + 1e-12f);

    float* orow = out + (size_t)row * HDIM;
#pragma unroll
    for (int p = 0; p < 3; p++) {
        const int c0 = (p * 64 + lane) * 4;
        float4 gg = *(const float4*)(g + c0);
        float4 bb = *(const float4*)(b + c0);
        float4 o;
        o.x = (v[p * 4 + 0] - mean) * rs * gg.x + bb.x;
        o.y = (v[p * 4 + 1] - mean) * rs * gg.y + bb.y;
        o.z = (v[p * 4 + 2] - mean) * rs * gg.z + bb.z;
        o.w = (v[p * 4 + 3] - mean) * rs * gg.w + bb.w;
        *(float4*)(orow + c0) = o;
    }
}

extern "C" void kernel_launch(void* const* d_in, const int* in_sizes, int n_in,
                              void* d_out, int out_size, void* d_ws, size_t ws_size,
                              hipStream_t stream) {
    (void)in_sizes; (void)n_in; (void)out_size; (void)ws_size;
    const float* A   = (const float*)d_in[0];
    const int* i_ty  = (const int*)d_in[1];
    const int* i_la  = (const int*)d_in[2];
    const int* i_op  = (const int*)d_in[3];
    const int* i_in  = (const int*)d_in[4];
    const int* i_ou  = (const int*)d_in[5];
    const int* negs  = (const int*)d_in[6];
    const float* te  = (const float*)d_in[7];
    const float* le  = (const float*)d_in[8];
    const float* oe  = (const float*)d_in[9];
    const float* ie  = (const float*)d_in[10];
    const float* ooe = (const float*)d_in[11];
    const float* pw  = (const float*)d_in[12];
    const float* pb  = (const float*)d_in[13];
    const float* nw  = (const float*)d_in[14];
    const float* nb  = (const float*)d_in[15];
    const float* lng = (const float*)d_in[16];
    const float* lnb = (const float*)d_in[17];
    float* out = (float*)d_out;

    // workspace layout (total ~100.1 MiB)
    char* ws = (char*)d_ws;
    u16* Wb  = (u16*)ws;                                   // 768*2016*2  = 3,096,576
    u16* NWb = (u16*)(ws + 3096576);                       // 768*768*2   = 1,179,648
    u16* Xb  = (u16*)(ws + 3096576 + 1179648);             // 32768*768*2 = 50,331,648
    u16* Yb  = (u16*)(ws + 3096576 + 1179648 + 50331648);  // 50,331,648

    cvt_weights<<<768, 256, 0, stream>>>(pw, nw, Wb, NWb);
    gemm1<<<1536, 256, 0, stream>>>(A, Wb, pb, i_ty, i_la, i_op, i_in, i_ou,
                                    te, le, oe, ie, ooe, Xb);
    gemm2<<<1536, 256, 0, stream>>>(Xb, NWb, nb, Yb);
    ln_k<<<8192, 256, 0, stream>>>(Xb, Yb, negs, lng, lnb, out);
}

// Round 2
// 676.769 us; speedup vs baseline: 1.3804x; 1.3804x over previous
//
#include <hip/hip_runtime.h>
#include <stdint.h>

typedef unsigned short u16;
typedef short v8s __attribute__((ext_vector_type(8)));
typedef float v4f __attribute__((ext_vector_type(4)));

typedef __attribute__((address_space(1))) uint32_t g_u32;
typedef __attribute__((address_space(3))) uint32_t l_u32;

// async global->LDS, 16B per lane; LDS dest = wave-uniform base + lane*16
__device__ __forceinline__ void glds16(const void* g, void* l) {
    __builtin_amdgcn_global_load_lds((const g_u32*)g, (l_u32*)l, 16, 0, 0);
}

// scalar fp32 -> bf16, round-to-nearest-even
__device__ __forceinline__ u16 f2b(float f) {
    uint32_t u = __builtin_bit_cast(uint32_t, f);
    u += 0x7FFFu + ((u >> 16) & 1u);
    return (u16)(u >> 16);
}

// pack two fp32 -> two bf16 in one u32 (round-half-up)
__device__ __forceinline__ uint32_t pk2(float a, float b) {
    uint32_t ua = __builtin_bit_cast(uint32_t, a) + 0x8000u;
    uint32_t ub = __builtin_bit_cast(uint32_t, b) + 0x8000u;
    return __builtin_amdgcn_perm(ub, ua, 0x07060302u);  // lo = ua.hi16, hi = ub.hi16
}

#define MTOT  32768
#define HDIM  768
#define KDIM  2000
#define KPAD  2016

// ---------------- K0: convert weights to bf16 (proj_w padded K 2000->2016, zeros) -------
__global__ __launch_bounds__(256) void cvt_weights(
    const float* __restrict__ pw, const float* __restrict__ nw,
    u16* __restrict__ Wb, u16* __restrict__ NWb)
{
    const int h = blockIdx.x;  // 768 blocks
    const float* src = pw + (size_t)h * KDIM;
    u16* dst = Wb + (size_t)h * KPAD;
    for (int k = threadIdx.x; k < KPAD; k += 256)
        dst[k] = (k < KDIM) ? f2b(src[k]) : (u16)0;
    const float* s2 = nw + (size_t)h * HDIM;
    u16* d2 = NWb + (size_t)h * HDIM;
    for (int k = threadIdx.x; k < HDIM; k += 256)
        d2[k] = f2b(s2[k]);
}

// ---------------- K1: GEMM1  x[m,h] = A[m,:] . Wb[h,:] + bias + 5 gathers ---------------
// 128x128 tile, BK=32. A staged as fp32 via glds (bank-swizzled), converted to bf16
// during fragment load. B staged bf16 via glds (bank-swizzled). Tail k>=2000: A source
// clamped (safe garbage), Wb zero-padded -> contributes 0.
__global__ __launch_bounds__(256, 3) void gemm1(
    const float* __restrict__ A, const u16* __restrict__ Wb,
    const float* __restrict__ pb,
    const int* __restrict__ i_ty, const int* __restrict__ i_la,
    const int* __restrict__ i_op, const int* __restrict__ i_in, const int* __restrict__ i_ou,
    const float* __restrict__ te, const float* __restrict__ le, const float* __restrict__ oe,
    const float* __restrict__ ie, const float* __restrict__ ooe,
    u16* __restrict__ Xb)
{
    __shared__ __align__(16) float Asf[128 * 32];  // 16 KB, row = 128B = 8 x 16B chunks
    __shared__ __align__(16) u16  Bs[128 * 32];    //  8 KB, row =  64B = 4 x 16B chunks

    // XCD-aware swizzle: 6 n-tiles of one m-panel land back-to-back on one XCD
    const int bid = blockIdx.x;            // 1536 = 256 m-tiles * 6 n-tiles
    const int slot = bid >> 3;             // 0..191
    const int mt = (bid & 7) * 32 + slot / 6;
    const int nt = slot % 6;
    const int m_base = mt * 128, n_base = nt * 128;

    const int tid = threadIdx.x;
    const int w = tid >> 6, lane = tid & 63;
    const int lm = lane & 15, quad = lane >> 4;
    const int wm = (w >> 1) * 64, wn = (w & 1) * 64;

    // A staging: wave w covers local rows [w*32, w*32+32), 4 glds (8 rows each).
    // Lane: rowl = base + (lane>>3), LDS slot s = lane&7 holds global chunk s^(rowl&7).
    const float* aRowBase[4];
    int aChunkOff[4];
    float* aDst[4];
#pragma unroll
    for (int t = 0; t < 4; t++) {
        const int rl = w * 32 + t * 8 + (lane >> 3);
        const int c16 = (lane & 7) ^ (rl & 7);
        aRowBase[t] = A + (size_t)(m_base + rl) * KDIM;
        aChunkOff[t] = c16 * 4;
        aDst[t] = &Asf[(w * 32 + t * 8) * 32];
    }
    // B staging: 2 glds (16 rows each). Slot s = lane&3 holds chunk s^((rowl>>1)&3).
    const u16* bSrc[2];
    u16* bDst[2];
#pragma unroll
    for (int t = 0; t < 2; t++) {
        const int rl = w * 32 + t * 16 + (lane >> 2);
        const int c = (lane & 3) ^ ((rl >> 1) & 3);
        bSrc[t] = Wb + (size_t)(n_base + rl) * KPAD + c * 8;
        bDst[t] = &Bs[(w * 32 + t * 16) * 32];
    }

    v4f acc[4][4];
#pragma unroll
    for (int i = 0; i < 4; i++)
#pragma unroll
        for (int j = 0; j < 4; j++) acc[i][j] = (v4f){0.f, 0.f, 0.f, 0.f};

    for (int kb = 0; kb < KPAD / 32; ++kb) {
        __syncthreads();  // prev iter's fragment reads done
#pragma unroll
        for (int t = 0; t < 4; t++) {
            int k = kb * 32 + aChunkOff[t];
            k = (k > 1996) ? 1996 : k;            // clamp tail: garbage * 0-padded B
            glds16(aRowBase[t] + k, aDst[t]);
        }
#pragma unroll
        for (int t = 0; t < 2; t++)
            glds16(bSrc[t] + kb * 32, bDst[t]);
        __syncthreads();  // glds drained

        v8s af[4], bf[4];
#pragma unroll
        for (int i = 0; i < 4; i++) {
            const int r = wm + i * 16 + lm;
            const int sw = r & 7;
            const float4 lo = *(const float4*)&Asf[r * 32 + (((2 * quad)     ^ sw) << 2)];
            const float4 hi = *(const float4*)&Asf[r * 32 + (((2 * quad + 1) ^ sw) << 2)];
            int4 p;
            p.x = (int)pk2(lo.x, lo.y); p.y = (int)pk2(lo.z, lo.w);
            p.z = (int)pk2(hi.x, hi.y); p.w = (int)pk2(hi.z, hi.w);
            af[i] = __builtin_bit_cast(v8s, p);
        }
#pragma unroll
        for (int j = 0; j < 4; j++) {
            const int r = wn + j * 16 + lm;
            bf[j] = *(const v8s*)&Bs[r * 32 + (quad ^ ((r >> 1) & 3)) * 8];
        }
#pragma unroll
        for (int i = 0; i < 4; i++)
#pragma unroll
            for (int j = 0; j < 4; j++)
                acc[i][j] = __builtin_amdgcn_mfma_f32_16x16x32_bf16(af[i], bf[j], acc[i][j], 0, 0, 0);
    }

    // epilogue: + proj_b + 5 table gathers, write bf16 x
#pragma unroll
    for (int i = 0; i < 4; i++) {
#pragma unroll
        for (int r = 0; r < 4; r++) {
            const int row = m_base + wm + i * 16 + quad * 4 + r;
            const int ty = i_ty[row], la = i_la[row], op = i_op[row];
            const int di = i_in[row], doo = i_ou[row];
            const float* pte = te + (size_t)ty * HDIM;
            const float* ple = le + (size_t)la * HDIM;
            const float* poe = oe + (size_t)op * HDIM;
            const float* pie = ie + (size_t)di * HDIM;
            const float* pou = ooe + (size_t)doo * HDIM;
            u16* orow = Xb + (size_t)row * HDIM;
#pragma unroll
            for (int j = 0; j < 4; j++) {
                const int col = n_base + wn + j * 16 + lm;
                float v = acc[i][j][r] + pb[col] + pte[col] + ple[col] + poe[col] + pie[col] + pou[col];
                orow[col] = f2b(v);
            }
        }
    }
}

// ---------------- K2: GEMM2  y[m,g] = xb[m,:] . NWb[g,:] + neg_b  (bf16, swizzled) ------
__global__ __launch_bounds__(256, 3) void gemm2(
    const u16* __restrict__ Xb, const u16* __restrict__ NWb,
    const float* __restrict__ nb, u16* __restrict__ Yb)
{
    __shared__ __align__(16) u16 As[128 * 32];
    __shared__ __align__(16) u16 Bs[128 * 32];

    const int bid = blockIdx.x;
    const int slot = bid >> 3;
    const int mt = (bid & 7) * 32 + slot / 6;
    const int nt = slot % 6;
    const int m_base = mt * 128, n_base = nt * 128;

    const int tid = threadIdx.x;
    const int w = tid >> 6, lane = tid & 63;
    const int lm = lane & 15, quad = lane >> 4;
    const int wm = (w >> 1) * 64, wn = (w & 1) * 64;

    const u16* aSrc[2]; u16* aDst[2];
    const u16* bSrc[2]; u16* bDst[2];
#pragma unroll
    for (int t = 0; t < 2; t++) {
        const int rl = w * 32 + t * 16 + (lane >> 2);
        const int c = (lane & 3) ^ ((rl >> 1) & 3);
        aSrc[t] = Xb  + (size_t)(m_base + rl) * HDIM + c * 8;
        aDst[t] = &As[(w * 32 + t * 16) * 32];
        bSrc[t] = NWb + (size_t)(n_base + rl) * HDIM + c * 8;
        bDst[t] = &Bs[(w * 32 + t * 16) * 32];
    }

    v4f acc[4][4];
#pragma unroll
    for (int i = 0; i < 4; i++)
#pragma unroll
        for (int j = 0; j < 4; j++) acc[i][j] = (v4f){0.f, 0.f, 0.f, 0.f};

    for (int kb = 0; kb < HDIM / 32; ++kb) {
        __syncthreads();
#pragma unroll
        for (int t = 0; t < 2; t++) {
            glds16(aSrc[t] + kb * 32, aDst[t]);
            glds16(bSrc[t] + kb * 32, bDst[t]);
        }
        __syncthreads();

        v8s af[4], bf[4];
#pragma unroll
        for (int i = 0; i < 4; i++) {
            const int r = wm + i * 16 + lm;
            af[i] = *(const v8s*)&As[r * 32 + (quad ^ ((r >> 1) & 3)) * 8];
        }
#pragma unroll
        for (int j = 0; j < 4; j++) {
            const int r = wn + j * 16 + lm;
            bf[j] = *(const v8s*)&Bs[r * 32 + (quad ^ ((r >> 1) & 3)) * 8];
        }
#pragma unroll
        for (int i = 0; i < 4; i++)
#pragma unroll
            for (int j = 0; j < 4; j++)
                acc[i][j] = __builtin_amdgcn_mfma_f32_16x16x32_bf16(af[i], bf[j], acc[i][j], 0, 0, 0);
    }

#pragma unroll
    for (int i = 0; i < 4; i++) {
#pragma unroll
        for (int r = 0; r < 4; r++) {
            const int row = m_base + wm + i * 16 + quad * 4 + r;
            u16* orow = Yb + (size_t)row * HDIM;
#pragma unroll
            for (int j = 0; j < 4; j++) {
                const int col = n_base + wn + j * 16 + lm;
                orow[col] = f2b(acc[i][j][r] + nb[col]);
            }
        }
    }
}

// ---------------- K3: select (negs) + LayerNorm, one wave per row -----------------------
__global__ __launch_bounds__(256) void ln_k(
    const u16* __restrict__ Xb, const u16* __restrict__ Yb,
    const int* __restrict__ negs,
    const float* __restrict__ g, const float* __restrict__ b,
    float* __restrict__ out)
{
    const int w = threadIdx.x >> 6, lane = threadIdx.x & 63;
    const int row = blockIdx.x * 4 + w;
    const u16* src = ((negs[row] == 1) ? Yb : Xb) + (size_t)row * HDIM;

    float v[12];
    float s = 0.f, ss = 0.f;
#pragma unroll
    for (int p = 0; p < 3; p++) {
        uint2 u = *(const uint2*)(src + (p * 64 + lane) * 4);
        float f0 = __builtin_bit_cast(float, u.x << 16);
        float f1 = __builtin_bit_cast(float, u.x & 0xFFFF0000u);
        float f2 = __builtin_bit_cast(float, u.y << 16);
        float f3 = __builtin_bit_cast(float, u.y & 0xFFFF0000u);
        v[p * 4 + 0] = f0; v[p * 4 + 1] = f1; v[p * 4 + 2] = f2; v[p * 4 + 3] = f3;
        s += f0 + f1 + f2 + f3;
        ss += f0 * f0 + f1 * f1 + f2 * f2 + f3 * f3;
    }
#pragma unroll
    for (int off = 1; off < 64; off <<= 1) {
        s += __shfl_xor(s, off);
        ss += __shfl_xor(ss, off);
    }
    const float mean = s * (1.f / (float)HDIM);
    const float var = ss * (1.f / (float)HDIM) - mean * mean;
    const float rs = rsqrtf(var + 1e-12f);

    float* orow = out + (size_t)row * HDIM;
#pragma unroll
    for (int p = 0; p < 3; p++) {
        const int c0 = (p * 64 + lane) * 4;
        float4 gg = *(const float4*)(g + c0);
        float4 bb = *(const float4*)(b + c0);
        float4 o;
        o.x = (v[p * 4 + 0] - mean) * rs * gg.x + bb.x;
        o.y = (v[p * 4 + 1] - mean) * rs * gg.y + bb.y;
        o.z = (v[p * 4 + 2] - mean) * rs * gg.z + bb.z;
        o.w = (v[p * 4 + 3] - mean) * rs * gg.w + bb.w;
        *(float4*)(orow + c0) = o;
    }
}

extern "C" void kernel_launch(void* const* d_in, const int* in_sizes, int n_in,
                              void* d_out, int out_size, void* d_ws, size_t ws_size,
                              hipStream_t stream) {
    (void)in_sizes; (void)n_in; (void)out_size; (void)ws_size;
    const float* A   = (const float*)d_in[0];
    const int* i_ty  = (const int*)d_in[1];
    const int* i_la  = (const int*)d_in[2];
    const int* i_op  = (const int*)d_in[3];
    const int* i_in  = (const int*)d_in[4];
    const int* i_ou  = (const int*)d_in[5];
    const int* negs  = (const int*)d_in[6];
    const float* te  = (const float*)d_in[7];
    const float* le  = (const float*)d_in[8];
    const float* oe  = (const float*)d_in[9];
    const float* ie  = (const float*)d_in[10];
    const float* ooe = (const float*)d_in[11];
    const float* pw  = (const float*)d_in[12];
    const float* pb  = (const float*)d_in[13];
    const float* nw  = (const float*)d_in[14];
    const float* nb  = (const float*)d_in[15];
    const float* lng = (const float*)d_in[16];
    const float* lnb = (const float*)d_in[17];
    float* out = (float*)d_out;

    // workspace layout (total ~100.1 MiB)
    char* ws = (char*)d_ws;
    u16* Wb  = (u16*)ws;                                   // 768*2016*2  = 3,096,576
    u16* NWb = (u16*)(ws + 3096576);                       // 768*768*2   = 1,179,648
    u16* Xb  = (u16*)(ws + 3096576 + 1179648);             // 32768*768*2 = 50,331,648
    u16* Yb  = (u16*)(ws + 3096576 + 1179648 + 50331648);  // 50,331,648

    cvt_weights<<<768, 256, 0, stream>>>(pw, nw, Wb, NWb);
    gemm1<<<1536, 256, 0, stream>>>(A, Wb, pb, i_ty, i_la, i_op, i_in, i_ou,
                                    te, le, oe, ie, ooe, Xb);
    gemm2<<<1536, 256, 0, stream>>>(Xb, NWb, nb, Yb);
    ln_k<<<8192, 256, 0, stream>>>(Xb, Yb, negs, lng, lnb, out);
}